// Round 1
// baseline (1783.120 us; speedup 1.0000x reference)
//
#include <hip/hip_runtime.h>
#include <hip/hip_bf16.h>

#define N_GRAPHS 200
#define NPG      500
#define N_NODES_ 100000
#define N_EDGES_ 1600000
#define DIN      64
#define DG       128
#define SEQ      20
#define HL       128
#define G4       512
#define NBKT     4
#define NPB      125
#define NBLK     (N_GRAPHS*NBKT)   // 800
#define BWIN     (N_GRAPHS - SEQ + 1)  // 181

__device__ __forceinline__ float sigmoidf_(float v){ return 1.0f/(1.0f+expf(-v)); }

// K1: degrees + per-bucket edge counts
__global__ void k_deg(const int* __restrict__ src, const int* __restrict__ dst,
                      int* outdeg, int* indeg, int* gcnt) {
  int e = blockIdx.x*blockDim.x + threadIdx.x;
  if (e >= N_EDGES_) return;
  int s = src[e], d = dst[e];
  atomicAdd(&outdeg[s], 1);
  atomicAdd(&indeg[d], 1);
  int g = d / NPG;
  int loc = d - g*NPG;
  atomicAdd(&gcnt[g*NBKT + loc/NPB], 1);
}

// K2: exclusive scan over 800 bucket counts (Hillis-Steele in LDS)
__global__ void k_scan(const int* __restrict__ gcnt, int* goff, int* gfill) {
  __shared__ int a[NBLK], b[NBLK];
  int t = threadIdx.x;
  int v = 0;
  if (t < NBLK) { v = gcnt[t]; a[t] = v; }
  __syncthreads();
  int* cur = a; int* nxt = b;
  for (int off = 1; off < NBLK; off <<= 1) {
    if (t < NBLK) nxt[t] = cur[t] + ((t >= off) ? cur[t-off] : 0);
    __syncthreads();
    int* tmp = cur; cur = nxt; nxt = tmp;
  }
  if (t < NBLK) {
    int incl = cur[t];
    int excl = incl - v;
    goff[t] = excl; gfill[t] = excl;
    if (t == NBLK-1) goff[NBLK] = incl;
  }
}

// K3: scatter edges into bucket-sorted list, packed (src<<7 | dst_local)
__global__ void k_scatter(const int* __restrict__ src, const int* __restrict__ dst,
                          int* gfill, int* __restrict__ epk) {
  int e = blockIdx.x*blockDim.x + threadIdx.x;
  if (e >= N_EDGES_) return;
  int s = src[e], d = dst[e];
  int g = d / NPG;
  int loc = d - g*NPG;
  int bkt = g*NBKT + loc/NPB;
  int dl = loc % NPB;
  int pos = atomicAdd(&gfill[bkt], 1);
  epk[pos] = (s << 7) | dl;
}

// K4: degree -> rsqrt scales (clamped to >=1)
__global__ void k_scale(const int* __restrict__ outdeg, const int* __restrict__ indeg,
                        float* so, float* si) {
  int n = blockIdx.x*blockDim.x + threadIdx.x;
  if (n >= N_NODES_) return;
  so[n] = rsqrtf((float)max(outdeg[n], 1));
  si[n] = rsqrtf((float)max(indeg[n], 1));
}

// K5: per-bucket edge aggregation into LDS; hpre = agg * scale_in
__global__ __launch_bounds__(512) void k_agg(const float* __restrict__ x,
    const float* __restrict__ so, const float* __restrict__ si,
    const int* __restrict__ goff, const int* __restrict__ epk,
    float* __restrict__ hpre) {
  __shared__ float sAgg[NPB*DIN];   // 32 KB
  int t = threadIdx.x, bb = blockIdx.x;
  for (int i = t; i < NPB*DIN; i += 512) sAgg[i] = 0.0f;
  __syncthreads();
  int lane = t & 63, w = t >> 6;
  int i0 = goff[bb], i1 = goff[bb+1];
  for (int i = i0 + (w<<2); i < i1; i += 32) {
    int pj[4]; float vj[4];
    #pragma unroll
    for (int j = 0; j < 4; ++j) pj[j] = (i + j < i1) ? epk[i+j] : -1;
    #pragma unroll
    for (int j = 0; j < 4; ++j) if (pj[j] >= 0) {
      int s = pj[j] >> 7;
      vj[j] = x[(size_t)s*DIN + lane] * so[s];
    }
    #pragma unroll
    for (int j = 0; j < 4; ++j) if (pj[j] >= 0)
      unsafeAtomicAdd(&sAgg[(pj[j] & 127)*DIN + lane], vj[j]);
  }
  __syncthreads();
  int g = bb >> 2, bkt = bb & 3;
  int nbase = g*NPG + bkt*NPB;
  for (int i = t; i < NPB*DIN; i += 512) {
    int n = nbase + (i >> 6);
    hpre[(size_t)n*DIN + (i & 63)] = sAgg[i] * si[n];
  }
}

// K6: per-bucket GEMM (hpre @ w_gcn + b), ReLU, partial pool
__global__ __launch_bounds__(512) void k_gcn(const float* __restrict__ hpre,
    const float* __restrict__ w_gcn, const float* __restrict__ b_gcn,
    float* __restrict__ hgpart) {
  __shared__ float wS[DIN*DG];   // 32 KB
  __shared__ float pS[4*DG];
  int t = threadIdx.x, bb = blockIdx.x;
  for (int i = t; i < DIN*DG; i += 512) wS[i] = w_gcn[i];
  __syncthreads();
  int d = t & 127, q = t >> 7;
  int g = bb >> 2, bkt = bb & 3;
  int nbase = g*NPG + bkt*NPB;
  float bgd = b_gcn[d];
  float psum = 0.0f;
  for (int n = q; n < NPB; n += 4) {
    const float4* hp = (const float4*)(hpre + (size_t)(nbase+n)*DIN);
    float acc = bgd;
    #pragma unroll
    for (int k4 = 0; k4 < 16; ++k4) {
      float4 h4 = hp[k4];
      int k = k4*4;
      acc += h4.x*wS[k*DG+d] + h4.y*wS[(k+1)*DG+d]
           + h4.z*wS[(k+2)*DG+d] + h4.w*wS[(k+3)*DG+d];
    }
    psum += fmaxf(acc, 0.0f);
  }
  pS[q*DG + d] = psum;
  __syncthreads();
  if (t < DG) hgpart[bb*DG + t] = pS[t] + pS[DG+t] + pS[2*DG+t] + pS[3*DG+t];
}

// K6b: combine 4 bucket partials, divide by node count
__global__ void k_pool(const float* __restrict__ hgpart, float* __restrict__ hg) {
  int idx = blockIdx.x*blockDim.x + threadIdx.x;
  if (idx >= N_GRAPHS*DG) return;
  int g = idx >> 7, d = idx & 127;
  float s = hgpart[(g*4+0)*DG+d] + hgpart[(g*4+1)*DG+d]
          + hgpart[(g*4+2)*DG+d] + hgpart[(g*4+3)*DG+d];
  hg[idx] = s * (1.0f/NPG);
}

// K7: per-graph input projection proj[g][r] = w_ih[r,:]·hg[g] + b_ih[r]
__global__ __launch_bounds__(512) void k_proj(const float* __restrict__ hg,
    const float* __restrict__ w_ih, const float* __restrict__ b_ih,
    float* __restrict__ proj) {
  __shared__ __align__(16) float hS[HL];
  int g = blockIdx.x, r = threadIdx.x;
  if (r < HL) hS[r] = hg[g*HL + r];
  __syncthreads();
  const float4* wr = (const float4*)(w_ih + (size_t)r*HL);
  const float4* hv = (const float4*)hS;
  float acc = b_ih[r];
  #pragma unroll
  for (int k4 = 0; k4 < 32; ++k4) {
    float4 w4 = wr[k4]; float4 h4 = hv[k4];
    acc += w4.x*h4.x + w4.y*h4.y + w4.z*h4.z + w4.w*h4.w;
  }
  proj[(size_t)g*G4 + r] = acc;
}

// K8: LSTM, block per window, thread per gate-row, w_hh row in VGPRs
__global__ __launch_bounds__(512) void k_lstm(const float* __restrict__ proj,
    const float* __restrict__ w_hh, const float* __restrict__ b_hh,
    const float* __restrict__ w_fc, const float* __restrict__ b_fc,
    float* __restrict__ out) {
  __shared__ __align__(16) float hS[HL];
  __shared__ float gS[G4];
  int b = blockIdx.x, r = threadIdx.x;
  float wreg[HL];
  const float4* wr = (const float4*)(w_hh + (size_t)r*HL);
  #pragma unroll
  for (int k4 = 0; k4 < 32; ++k4) {
    float4 w4 = wr[k4];
    wreg[k4*4+0]=w4.x; wreg[k4*4+1]=w4.y; wreg[k4*4+2]=w4.z; wreg[k4*4+3]=w4.w;
  }
  float bh = b_hh[r];
  float c = 0.0f;
  if (r < HL) hS[r] = 0.0f;
  __syncthreads();
  for (int l = 0; l < SEQ; ++l) {
    float acc = proj[(size_t)(b+l)*G4 + r] + bh;
    const float4* hv = (const float4*)hS;
    #pragma unroll
    for (int k4 = 0; k4 < 32; ++k4) {
      float4 h4 = hv[k4];
      acc += h4.x*wreg[k4*4] + h4.y*wreg[k4*4+1] + h4.z*wreg[k4*4+2] + h4.w*wreg[k4*4+3];
    }
    gS[r] = acc;
    __syncthreads();
    if (r < HL) {
      float gi = sigmoidf_(gS[r]);
      float gf = sigmoidf_(gS[HL + r]);
      float gg = tanhf(gS[2*HL + r]);
      float go = sigmoidf_(gS[3*HL + r]);
      c = gf*c + gi*gg;
      hS[r] = go * tanhf(c);
    }
    __syncthreads();
  }
  if (r < 64) {
    float s = hS[r]*w_fc[r] + hS[r+64]*w_fc[r+64];
    #pragma unroll
    for (int off = 32; off > 0; off >>= 1) s += __shfl_down(s, off);
    if (r == 0) out[b] = s + b_fc[0];
  }
}

extern "C" void kernel_launch(void* const* d_in, const int* in_sizes, int n_in,
                              void* d_out, int out_size, void* d_ws, size_t ws_size,
                              hipStream_t stream) {
  const float* x     = (const float*)d_in[0];
  const int*   src   = (const int*)d_in[1];
  const int*   dst   = (const int*)d_in[2];
  // d_in[3] graph_ids: implicit (n / 500), unused
  const float* w_gcn = (const float*)d_in[4];
  const float* b_gcn = (const float*)d_in[5];
  const float* w_ih  = (const float*)d_in[6];
  const float* w_hh  = (const float*)d_in[7];
  const float* b_ih  = (const float*)d_in[8];
  const float* b_hh  = (const float*)d_in[9];
  const float* w_fc  = (const float*)d_in[10];
  const float* b_fc  = (const float*)d_in[11];
  float* out = (float*)d_out;

  char* ws = (char*)d_ws;
  size_t off = 0;
  auto alloc = [&](size_t bytes) -> void* {
    void* p = ws + off; off += (bytes + 255) & ~(size_t)255; return p;
  };
  // zeroed region first (gcnt, outdeg, indeg)
  int* gcnt   = (int*)alloc((size_t)NBLK*4);
  int* outdeg = (int*)alloc((size_t)N_NODES_*4);
  int* indeg  = (int*)alloc((size_t)N_NODES_*4);
  size_t zero_bytes = off;
  int* gfill  = (int*)alloc((size_t)NBLK*4);
  int* goff   = (int*)alloc((size_t)(NBLK+1)*4);
  float* so   = (float*)alloc((size_t)N_NODES_*4);
  float* si   = (float*)alloc((size_t)N_NODES_*4);
  int* epk    = (int*)alloc((size_t)N_EDGES_*4);
  float* hpre = (float*)alloc((size_t)N_NODES_*DIN*4);
  float* hgpart = (float*)alloc((size_t)NBLK*DG*4);
  float* hg   = (float*)alloc((size_t)N_GRAPHS*DG*4);
  float* proj = (float*)alloc((size_t)N_GRAPHS*G4*4);
  (void)ws_size; (void)in_sizes; (void)n_in; (void)out_size;

  hipMemsetAsync(d_ws, 0, zero_bytes, stream);
  k_deg<<<(N_EDGES_+255)/256, 256, 0, stream>>>(src, dst, outdeg, indeg, gcnt);
  k_scan<<<1, 1024, 0, stream>>>(gcnt, goff, gfill);
  k_scatter<<<(N_EDGES_+255)/256, 256, 0, stream>>>(src, dst, gfill, epk);
  k_scale<<<(N_NODES_+255)/256, 256, 0, stream>>>(outdeg, indeg, so, si);
  k_agg<<<NBLK, 512, 0, stream>>>(x, so, si, goff, epk, hpre);
  k_gcn<<<NBLK, 512, 0, stream>>>(hpre, w_gcn, b_gcn, hgpart);
  k_pool<<<(N_GRAPHS*DG+255)/256, 256, 0, stream>>>(hgpart, hg);
  k_proj<<<N_GRAPHS, 512, 0, stream>>>(hg, w_ih, b_ih, proj);
  k_lstm<<<BWIN, 512, 0, stream>>>(proj, w_hh, b_hh, w_fc, b_fc, out);
}

// Round 2
// 518.038 us; speedup vs baseline: 3.4421x; 3.4421x over previous
//
#include <hip/hip_runtime.h>
#include <hip/hip_bf16.h>

#define N_GRAPHS 200
#define NPG      500
#define N_NODES_ 100000
#define N_EDGES_ 1600000
#define DIN      64
#define DG       128
#define SEQ      20
#define HL       128
#define G4       512
#define BWIN     (N_GRAPHS - SEQ + 1)  // 181
#define NCHUNK   98                    // ceil(100000/1024)
#define GPARTS   8                     // blocks per graph in k_gcn
#define NPPART   63                    // ceil(500/8)

__device__ __forceinline__ float sigmoidf_(float v){ return 1.0f/(1.0f+expf(-v)); }

// K1: degrees
__global__ void k_deg(const int* __restrict__ src, const int* __restrict__ dst,
                      int* outdeg, int* indeg) {
  int e = blockIdx.x*blockDim.x + threadIdx.x;
  if (e >= N_EDGES_) return;
  atomicAdd(&outdeg[src[e]], 1);
  atomicAdd(&indeg[dst[e]], 1);
}

// K2: degree -> rsqrt scales (clamped to >=1)
__global__ void k_scale(const int* __restrict__ outdeg, const int* __restrict__ indeg,
                        float* so, float* si) {
  int n = blockIdx.x*blockDim.x + threadIdx.x;
  if (n >= N_NODES_) return;
  so[n] = rsqrtf((float)max(outdeg[n], 1));
  si[n] = rsqrtf((float)max(indeg[n], 1));
}

// K3a: per-chunk (1024 nodes) sum of indeg
__global__ void k_chunksum(const int* __restrict__ indeg, int* __restrict__ chunksum) {
  __shared__ int red[256];
  int c = blockIdx.x, t = threadIdx.x;
  int base = c*1024 + t*4;
  int s = 0;
  #pragma unroll
  for (int j = 0; j < 4; ++j) { int n = base+j; if (n < N_NODES_) s += indeg[n]; }
  red[t] = s; __syncthreads();
  for (int off = 128; off > 0; off >>= 1) {
    if (t < off) red[t] += red[t+off];
    __syncthreads();
  }
  if (t == 0) chunksum[c] = red[0];
}

// K3b: exclusive scan of chunk sums (single block)
__global__ void k_chunkscan(const int* __restrict__ chunksum, int* __restrict__ chunkbase,
                            int* __restrict__ nodeoff) {
  __shared__ int a[128], b[128];
  int t = threadIdx.x;
  int v = (t < NCHUNK) ? chunksum[t] : 0;
  a[t] = v; __syncthreads();
  int* cur = a; int* nxt = b;
  for (int off = 1; off < 128; off <<= 1) {
    nxt[t] = cur[t] + ((t >= off) ? cur[t-off] : 0);
    __syncthreads();
    int* tmp = cur; cur = nxt; nxt = tmp;
  }
  if (t < NCHUNK) chunkbase[t] = cur[t] - v;
  if (t == 0) nodeoff[N_NODES_] = N_EDGES_;
}

// K3c: per-node exclusive offsets
__global__ void k_nodeoff(const int* __restrict__ indeg, const int* __restrict__ chunkbase,
                          int* __restrict__ nodeoff, int* __restrict__ nodefill) {
  __shared__ int a[256], b[256];
  int c = blockIdx.x, t = threadIdx.x;
  int base = c*1024 + t*4;
  int v[4]; int s = 0;
  #pragma unroll
  for (int j = 0; j < 4; ++j) {
    int n = base+j;
    v[j] = (n < N_NODES_) ? indeg[n] : 0;
    s += v[j];
  }
  a[t] = s; __syncthreads();
  int* cur = a; int* nxt = b;
  for (int off = 1; off < 256; off <<= 1) {
    nxt[t] = cur[t] + ((t >= off) ? cur[t-off] : 0);
    __syncthreads();
    int* tmp = cur; cur = nxt; nxt = tmp;
  }
  int run = chunkbase[c] + cur[t] - s;
  #pragma unroll
  for (int j = 0; j < 4; ++j) {
    int n = base+j;
    if (n < N_NODES_) { nodeoff[n] = run; nodefill[n] = run; run += v[j]; }
  }
}

// K4: scatter edge sources into per-dst segments
__global__ void k_scatter(const int* __restrict__ src, const int* __restrict__ dst,
                          int* nodefill, int* __restrict__ epk) {
  int e = blockIdx.x*blockDim.x + threadIdx.x;
  if (e >= N_EDGES_) return;
  int pos = atomicAdd(&nodefill[dst[e]], 1);
  epk[pos] = src[e];
}

// K5: atomic-free aggregation — one wave per node, quarter-wave per edge
__global__ __launch_bounds__(256) void k_agg(const float* __restrict__ x,
    const float* __restrict__ so, const float* __restrict__ si,
    const int* __restrict__ nodeoff, const int* __restrict__ epk,
    float* __restrict__ hpre) {
  int t = threadIdx.x;
  int wave = (blockIdx.x << 2) + (t >> 6);   // global wave id = node
  if (wave >= N_NODES_) return;
  int n = wave;
  int lane = t & 63, q = lane >> 4, ql = lane & 15;
  int o0 = nodeoff[n], o1 = nodeoff[n+1];
  float4 acc = make_float4(0.f, 0.f, 0.f, 0.f);
  const float4* x4 = (const float4*)x;
  for (int e = o0 + q; e < o1; e += 4) {
    int s = epk[e];
    float sc = so[s];
    float4 xv = x4[(size_t)s*16 + ql];
    acc.x += xv.x*sc; acc.y += xv.y*sc; acc.z += xv.z*sc; acc.w += xv.w*sc;
  }
  // reduce across the 4 quarters (lanes ql, ql+16, ql+32, ql+48)
  acc.x += __shfl_xor(acc.x, 16); acc.y += __shfl_xor(acc.y, 16);
  acc.z += __shfl_xor(acc.z, 16); acc.w += __shfl_xor(acc.w, 16);
  acc.x += __shfl_xor(acc.x, 32); acc.y += __shfl_xor(acc.y, 32);
  acc.z += __shfl_xor(acc.z, 32); acc.w += __shfl_xor(acc.w, 32);
  if (q == 0) {
    float sn = si[n];
    float4 r = make_float4(acc.x*sn, acc.y*sn, acc.z*sn, acc.w*sn);
    ((float4*)hpre)[(size_t)n*16 + ql] = r;
  }
}

// K6: GCN GEMM + ReLU + partial pool. w column in VGPRs, h row via uniform load.
__global__ __launch_bounds__(128) void k_gcn(const float* __restrict__ hpre,
    const float* __restrict__ w_gcn, const float* __restrict__ b_gcn,
    float* __restrict__ hgpart) {
  int d = threadIdx.x;                 // 0..127 output dim
  int bb = blockIdx.x;
  int g = bb >> 3, p = bb & 7;
  float wreg[DIN];
  #pragma unroll
  for (int k = 0; k < DIN; ++k) wreg[k] = w_gcn[k*DG + d];
  float bgd = b_gcn[d];
  float psum = 0.0f;
  int n0 = p*NPPART, n1 = min(n0 + NPPART, NPG);
  for (int n = n0; n < n1; ++n) {
    const float4* hp = (const float4*)(hpre + (size_t)(g*NPG + n)*DIN);
    float acc = bgd;
    #pragma unroll
    for (int k4 = 0; k4 < 16; ++k4) {
      float4 h4 = hp[k4];
      acc = fmaf(h4.x, wreg[4*k4+0], acc);
      acc = fmaf(h4.y, wreg[4*k4+1], acc);
      acc = fmaf(h4.z, wreg[4*k4+2], acc);
      acc = fmaf(h4.w, wreg[4*k4+3], acc);
    }
    psum += fmaxf(acc, 0.0f);
  }
  hgpart[(size_t)bb*DG + d] = psum;
}

// K7: combine partials, divide by node count
__global__ void k_pool(const float* __restrict__ hgpart, float* __restrict__ hg) {
  int idx = blockIdx.x*blockDim.x + threadIdx.x;
  if (idx >= N_GRAPHS*DG) return;
  int g = idx >> 7, d = idx & 127;
  float s = 0.0f;
  #pragma unroll
  for (int p = 0; p < GPARTS; ++p) s += hgpart[(size_t)(g*GPARTS+p)*DG + d];
  hg[idx] = s * (1.0f/NPG);
}

// K8: per-graph input projection proj[g][r] = w_ih[r,:]·hg[g] + b_ih[r]
__global__ __launch_bounds__(512) void k_proj(const float* __restrict__ hg,
    const float* __restrict__ w_ih, const float* __restrict__ b_ih,
    float* __restrict__ proj) {
  __shared__ __align__(16) float hS[HL];
  int g = blockIdx.x, r = threadIdx.x;
  if (r < HL) hS[r] = hg[g*HL + r];
  __syncthreads();
  const float4* wr = (const float4*)(w_ih + (size_t)r*HL);
  const float4* hv = (const float4*)hS;
  float acc = b_ih[r];
  #pragma unroll
  for (int k4 = 0; k4 < 32; ++k4) {
    float4 w4 = wr[k4]; float4 h4 = hv[k4];
    acc += w4.x*h4.x + w4.y*h4.y + w4.z*h4.z + w4.w*h4.w;
  }
  proj[(size_t)g*G4 + r] = acc;
}

// K9: LSTM, block per window, thread per gate-row, w_hh row in VGPRs
__global__ __launch_bounds__(512) void k_lstm(const float* __restrict__ proj,
    const float* __restrict__ w_hh, const float* __restrict__ b_hh,
    const float* __restrict__ w_fc, const float* __restrict__ b_fc,
    float* __restrict__ out) {
  __shared__ __align__(16) float hS[HL];
  __shared__ float gS[G4];
  int b = blockIdx.x, r = threadIdx.x;
  float wreg[HL];
  const float4* wr = (const float4*)(w_hh + (size_t)r*HL);
  #pragma unroll
  for (int k4 = 0; k4 < 32; ++k4) {
    float4 w4 = wr[k4];
    wreg[k4*4+0]=w4.x; wreg[k4*4+1]=w4.y; wreg[k4*4+2]=w4.z; wreg[k4*4+3]=w4.w;
  }
  float bh = b_hh[r];
  float c = 0.0f;
  if (r < HL) hS[r] = 0.0f;
  __syncthreads();
  for (int l = 0; l < SEQ; ++l) {
    float acc = proj[(size_t)(b+l)*G4 + r] + bh;
    const float4* hv = (const float4*)hS;
    #pragma unroll
    for (int k4 = 0; k4 < 32; ++k4) {
      float4 h4 = hv[k4];
      acc += h4.x*wreg[k4*4] + h4.y*wreg[k4*4+1] + h4.z*wreg[k4*4+2] + h4.w*wreg[k4*4+3];
    }
    gS[r] = acc;
    __syncthreads();
    if (r < HL) {
      float gi = sigmoidf_(gS[r]);
      float gf = sigmoidf_(gS[HL + r]);
      float gg = tanhf(gS[2*HL + r]);
      float go = sigmoidf_(gS[3*HL + r]);
      c = gf*c + gi*gg;
      hS[r] = go * tanhf(c);
    }
    __syncthreads();
  }
  if (r < 64) {
    float s = hS[r]*w_fc[r] + hS[r+64]*w_fc[r+64];
    #pragma unroll
    for (int off = 32; off > 0; off >>= 1) s += __shfl_down(s, off);
    if (r == 0) out[b] = s + b_fc[0];
  }
}

extern "C" void kernel_launch(void* const* d_in, const int* in_sizes, int n_in,
                              void* d_out, int out_size, void* d_ws, size_t ws_size,
                              hipStream_t stream) {
  const float* x     = (const float*)d_in[0];
  const int*   src   = (const int*)d_in[1];
  const int*   dst   = (const int*)d_in[2];
  const float* w_gcn = (const float*)d_in[4];
  const float* b_gcn = (const float*)d_in[5];
  const float* w_ih  = (const float*)d_in[6];
  const float* w_hh  = (const float*)d_in[7];
  const float* b_ih  = (const float*)d_in[8];
  const float* b_hh  = (const float*)d_in[9];
  const float* w_fc  = (const float*)d_in[10];
  const float* b_fc  = (const float*)d_in[11];
  float* out = (float*)d_out;

  char* ws = (char*)d_ws;
  size_t off = 0;
  auto alloc = [&](size_t bytes) -> void* {
    void* p = ws + off; off += (bytes + 255) & ~(size_t)255; return p;
  };
  // zeroed region first (outdeg, indeg)
  int* outdeg = (int*)alloc((size_t)N_NODES_*4);
  int* indeg  = (int*)alloc((size_t)N_NODES_*4);
  size_t zero_bytes = off;
  float* so    = (float*)alloc((size_t)N_NODES_*4);
  float* si    = (float*)alloc((size_t)N_NODES_*4);
  int* chunksum = (int*)alloc((size_t)NCHUNK*4);
  int* chunkbase= (int*)alloc((size_t)NCHUNK*4);
  int* nodeoff = (int*)alloc((size_t)(N_NODES_+1)*4);
  int* nodefill= (int*)alloc((size_t)N_NODES_*4);
  int* epk     = (int*)alloc((size_t)N_EDGES_*4);
  float* hpre  = (float*)alloc((size_t)N_NODES_*DIN*4);
  float* hgpart= (float*)alloc((size_t)N_GRAPHS*GPARTS*DG*4);
  float* hg    = (float*)alloc((size_t)N_GRAPHS*DG*4);
  float* proj  = (float*)alloc((size_t)N_GRAPHS*G4*4);
  (void)ws_size; (void)in_sizes; (void)n_in; (void)out_size;

  hipMemsetAsync(d_ws, 0, zero_bytes, stream);
  k_deg<<<(N_EDGES_+255)/256, 256, 0, stream>>>(src, dst, outdeg, indeg);
  k_scale<<<(N_NODES_+255)/256, 256, 0, stream>>>(outdeg, indeg, so, si);
  k_chunksum<<<NCHUNK, 256, 0, stream>>>(indeg, chunksum);
  k_chunkscan<<<1, 128, 0, stream>>>(chunksum, chunkbase, nodeoff);
  k_nodeoff<<<NCHUNK, 256, 0, stream>>>(indeg, chunkbase, nodeoff, nodefill);
  k_scatter<<<(N_EDGES_+255)/256, 256, 0, stream>>>(src, dst, nodefill, epk);
  k_agg<<<(N_NODES_+3)/4, 256, 0, stream>>>(x, so, si, nodeoff, epk, hpre);
  k_gcn<<<N_GRAPHS*GPARTS, 128, 0, stream>>>(hpre, w_gcn, b_gcn, hgpart);
  k_pool<<<(N_GRAPHS*DG+255)/256, 256, 0, stream>>>(hgpart, hg);
  k_proj<<<N_GRAPHS, 512, 0, stream>>>(hg, w_ih, b_ih, proj);
  k_lstm<<<BWIN, 512, 0, stream>>>(proj, w_hh, b_hh, w_fc, b_fc, out);
}

// Round 3
// 398.305 us; speedup vs baseline: 4.4768x; 1.3006x over previous
//
#include <hip/hip_runtime.h>
#include <hip/hip_bf16.h>

#define N_GRAPHS 200
#define NPG      500
#define N_NODES_ 100000
#define N_EDGES_ 1600000
#define DIN      64
#define DG       128
#define SEQ      20
#define HL       128
#define G4       512
#define BWIN     (N_GRAPHS - SEQ + 1)  // 181
#define NPART    64
#define EPB      (N_EDGES_/NPART)      // 25000
#define NCNT     (N_GRAPHS*NPART)      // 12800
#define SORT_CAP 10000
#define GPARTS   8
#define NPPART   63

__device__ __forceinline__ float sigmoidf_(float v){ return 1.0f/(1.0f+expf(-v)); }

// K1: per-(block,graph) edge counts via LDS histogram (no global atomics)
__global__ __launch_bounds__(256) void k_count(const int* __restrict__ src,
                                               int* __restrict__ cnt) {
  __shared__ int bins[N_GRAPHS];
  int b = blockIdx.x, t = threadIdx.x;
  for (int i = t; i < N_GRAPHS; i += 256) bins[i] = 0;
  __syncthreads();
  int e0 = b*EPB;
  for (int i = t; i < EPB; i += 256) atomicAdd(&bins[src[e0+i]/NPG], 1);
  __syncthreads();
  for (int g = t; g < N_GRAPHS; g += 256) cnt[g*NPART + b] = bins[g];
}

// K2: exclusive scan of 12800 counts in one block (13/thread + 1024-scan)
__global__ __launch_bounds__(1024) void k_pscan(int* __restrict__ cnt) {
  __shared__ int sA[1024], sB[1024];
  int t = threadIdx.x;
  int base = t*13;
  int loc[13]; int s = 0;
  #pragma unroll
  for (int j = 0; j < 13; ++j) {
    int idx = base + j;
    int v = (idx < NCNT) ? cnt[idx] : 0;
    loc[j] = s; s += v;
  }
  sA[t] = s; __syncthreads();
  int* cur = sA; int* nxt = sB;
  for (int off = 1; off < 1024; off <<= 1) {
    nxt[t] = cur[t] + ((t >= off) ? cur[t-off] : 0);
    __syncthreads();
    int* tmp = cur; cur = nxt; nxt = tmp;
  }
  int excl = cur[t] - s;
  #pragma unroll
  for (int j = 0; j < 13; ++j) {
    int idx = base + j;
    if (idx < NCNT) cnt[idx] = excl + loc[j];
  }
}

// K3: deterministic partition by graph; packed (src_local<<9 | dst_local)
__global__ __launch_bounds__(256) void k_part(const int* __restrict__ src,
                                              const int* __restrict__ dst,
                                              const int* __restrict__ cnt,
                                              int* __restrict__ part) {
  __shared__ int cur[N_GRAPHS];
  int b = blockIdx.x, t = threadIdx.x;
  for (int g = t; g < N_GRAPHS; g += 256) cur[g] = cnt[g*NPART + b];
  __syncthreads();
  int e0 = b*EPB;
  for (int i = t; i < EPB; i += 256) {
    int s = src[e0+i], d = dst[e0+i];
    int g = s / NPG;
    int sl = s - g*NPG, dl = d - g*NPG;
    int pos = atomicAdd(&cur[g], 1);
    part[pos] = (sl << 9) | dl;
  }
}

// K4: per-graph mega-kernel — degrees, scan, LDS counting sort, aggregation.
__global__ __launch_bounds__(512) void k_mega(const float* __restrict__ x,
    const int* __restrict__ cnt, const int* __restrict__ part,
    float* __restrict__ hpre) {
  __shared__ unsigned short sorted[SORT_CAP];
  __shared__ int indeg[NPG], outdeg[NPG], off[NPG];
  __shared__ float so[NPG];
  __shared__ int sA[512], sB[512];
  int g = blockIdx.x, t = threadIdx.x;
  int seg0 = cnt[g*NPART];
  int seg1 = (g == N_GRAPHS-1) ? N_EDGES_ : cnt[(g+1)*NPART];
  for (int i = t; i < NPG; i += 512) { indeg[i] = 0; outdeg[i] = 0; }
  __syncthreads();
  for (int e = seg0 + t; e < seg1; e += 512) {
    int p = part[e];
    atomicAdd(&indeg[p & 511], 1);
    atomicAdd(&outdeg[p >> 9], 1);
  }
  __syncthreads();
  // exclusive scan of indeg -> off; so = rsqrt(outdeg)
  int v = (t < NPG) ? indeg[t] : 0;
  sA[t] = v; __syncthreads();
  int* cur = sA; int* nxt = sB;
  for (int o = 1; o < 512; o <<= 1) {
    nxt[t] = cur[t] + ((t >= o) ? cur[t-o] : 0);
    __syncthreads();
    int* tmp = cur; cur = nxt; nxt = tmp;
  }
  if (t < NPG) {
    off[t] = cur[t] - v;
    so[t] = rsqrtf((float)max(outdeg[t], 1));
  }
  __syncthreads();
  // counting-sort scatter: sorted[pos] = src_local, grouped by dst_local
  for (int e = seg0 + t; e < seg1; e += 512) {
    int p = part[e];
    int pos = atomicAdd(&off[p & 511], 1);
    if (pos < SORT_CAP) sorted[pos] = (unsigned short)(p >> 9);
  }
  __syncthreads();
  // aggregation: one wave per node, quarter-wave x 4-unroll per edge
  int lane = t & 63, w = t >> 6, q = lane >> 4, ql = lane & 15;
  const float4* x4 = (const float4*)x;
  for (int n = w; n < NPG; n += 8) {
    int end = off[n], deg = indeg[n], start = end - deg;
    float4 acc = make_float4(0.f, 0.f, 0.f, 0.f);
    for (int i = start + (q << 2); i < end; i += 16) {
      int sj[4];
      #pragma unroll
      for (int j = 0; j < 4; ++j) sj[j] = (i + j < end) ? (int)sorted[i+j] : -1;
      #pragma unroll
      for (int j = 0; j < 4; ++j) if (sj[j] >= 0) {
        float sc = so[sj[j]];
        float4 xv = x4[(size_t)(g*NPG + sj[j])*16 + ql];
        acc.x += xv.x*sc; acc.y += xv.y*sc; acc.z += xv.z*sc; acc.w += xv.w*sc;
      }
    }
    acc.x += __shfl_xor(acc.x, 16); acc.y += __shfl_xor(acc.y, 16);
    acc.z += __shfl_xor(acc.z, 16); acc.w += __shfl_xor(acc.w, 16);
    acc.x += __shfl_xor(acc.x, 32); acc.y += __shfl_xor(acc.y, 32);
    acc.z += __shfl_xor(acc.z, 32); acc.w += __shfl_xor(acc.w, 32);
    if (q == 0) {
      float sn = rsqrtf((float)max(deg, 1));
      float4 r = make_float4(acc.x*sn, acc.y*sn, acc.z*sn, acc.w*sn);
      ((float4*)hpre)[(size_t)(g*NPG + n)*16 + ql] = r;
    }
  }
}

// K5: GCN GEMM + ReLU + partial pool. w column in VGPRs.
__global__ __launch_bounds__(128) void k_gcn(const float* __restrict__ hpre,
    const float* __restrict__ w_gcn, const float* __restrict__ b_gcn,
    float* __restrict__ hgpart) {
  int d = threadIdx.x;
  int bb = blockIdx.x;
  int g = bb >> 3, p = bb & 7;
  float wreg[DIN];
  #pragma unroll
  for (int k = 0; k < DIN; ++k) wreg[k] = w_gcn[k*DG + d];
  float bgd = b_gcn[d];
  float psum = 0.0f;
  int n0 = p*NPPART, n1 = min(n0 + NPPART, NPG);
  for (int n = n0; n < n1; ++n) {
    const float4* hp = (const float4*)(hpre + (size_t)(g*NPG + n)*DIN);
    float acc = bgd;
    #pragma unroll
    for (int k4 = 0; k4 < 16; ++k4) {
      float4 h4 = hp[k4];
      acc = fmaf(h4.x, wreg[4*k4+0], acc);
      acc = fmaf(h4.y, wreg[4*k4+1], acc);
      acc = fmaf(h4.z, wreg[4*k4+2], acc);
      acc = fmaf(h4.w, wreg[4*k4+3], acc);
    }
    psum += fmaxf(acc, 0.0f);
  }
  hgpart[(size_t)bb*DG + d] = psum;
}

// K6: combine partials, divide by node count
__global__ void k_pool(const float* __restrict__ hgpart, float* __restrict__ hg) {
  int idx = blockIdx.x*blockDim.x + threadIdx.x;
  if (idx >= N_GRAPHS*DG) return;
  int g = idx >> 7, d = idx & 127;
  float s = 0.0f;
  #pragma unroll
  for (int p = 0; p < GPARTS; ++p) s += hgpart[(size_t)(g*GPARTS+p)*DG + d];
  hg[idx] = s * (1.0f/NPG);
}

// K7: per-graph input projection
__global__ __launch_bounds__(512) void k_proj(const float* __restrict__ hg,
    const float* __restrict__ w_ih, const float* __restrict__ b_ih,
    float* __restrict__ proj) {
  __shared__ __align__(16) float hS[HL];
  int g = blockIdx.x, r = threadIdx.x;
  if (r < HL) hS[r] = hg[g*HL + r];
  __syncthreads();
  const float4* wr = (const float4*)(w_ih + (size_t)r*HL);
  const float4* hv = (const float4*)hS;
  float acc = b_ih[r];
  #pragma unroll
  for (int k4 = 0; k4 < 32; ++k4) {
    float4 w4 = wr[k4]; float4 h4 = hv[k4];
    acc += w4.x*h4.x + w4.y*h4.y + w4.z*h4.z + w4.w*h4.w;
  }
  proj[(size_t)g*G4 + r] = acc;
}

// K8: LSTM, block per window, thread per gate-row, w_hh row in VGPRs
__global__ __launch_bounds__(512) void k_lstm(const float* __restrict__ proj,
    const float* __restrict__ w_hh, const float* __restrict__ b_hh,
    const float* __restrict__ w_fc, const float* __restrict__ b_fc,
    float* __restrict__ out) {
  __shared__ __align__(16) float hS[HL];
  __shared__ float gS[G4];
  int b = blockIdx.x, r = threadIdx.x;
  float wreg[HL];
  const float4* wr = (const float4*)(w_hh + (size_t)r*HL);
  #pragma unroll
  for (int k4 = 0; k4 < 32; ++k4) {
    float4 w4 = wr[k4];
    wreg[k4*4+0]=w4.x; wreg[k4*4+1]=w4.y; wreg[k4*4+2]=w4.z; wreg[k4*4+3]=w4.w;
  }
  float bh = b_hh[r];
  float c = 0.0f;
  if (r < HL) hS[r] = 0.0f;
  __syncthreads();
  for (int l = 0; l < SEQ; ++l) {
    float acc = proj[(size_t)(b+l)*G4 + r] + bh;
    const float4* hv = (const float4*)hS;
    #pragma unroll
    for (int k4 = 0; k4 < 32; ++k4) {
      float4 h4 = hv[k4];
      acc += h4.x*wreg[k4*4] + h4.y*wreg[k4*4+1] + h4.z*wreg[k4*4+2] + h4.w*wreg[k4*4+3];
    }
    gS[r] = acc;
    __syncthreads();
    if (r < HL) {
      float gi = sigmoidf_(gS[r]);
      float gf = sigmoidf_(gS[HL + r]);
      float gg = tanhf(gS[2*HL + r]);
      float go = sigmoidf_(gS[3*HL + r]);
      c = gf*c + gi*gg;
      hS[r] = go * tanhf(c);
    }
    __syncthreads();
  }
  if (r < 64) {
    float s = hS[r]*w_fc[r] + hS[r+64]*w_fc[r+64];
    #pragma unroll
    for (int off = 32; off > 0; off >>= 1) s += __shfl_down(s, off);
    if (r == 0) out[b] = s + b_fc[0];
  }
}

extern "C" void kernel_launch(void* const* d_in, const int* in_sizes, int n_in,
                              void* d_out, int out_size, void* d_ws, size_t ws_size,
                              hipStream_t stream) {
  const float* x     = (const float*)d_in[0];
  const int*   src   = (const int*)d_in[1];
  const int*   dst   = (const int*)d_in[2];
  const float* w_gcn = (const float*)d_in[4];
  const float* b_gcn = (const float*)d_in[5];
  const float* w_ih  = (const float*)d_in[6];
  const float* w_hh  = (const float*)d_in[7];
  const float* b_ih  = (const float*)d_in[8];
  const float* b_hh  = (const float*)d_in[9];
  const float* w_fc  = (const float*)d_in[10];
  const float* b_fc  = (const float*)d_in[11];
  float* out = (float*)d_out;

  char* ws = (char*)d_ws;
  size_t off = 0;
  auto alloc = [&](size_t bytes) -> void* {
    void* p = ws + off; off += (bytes + 255) & ~(size_t)255; return p;
  };
  int* cnt     = (int*)alloc((size_t)NCNT*4);
  int* part    = (int*)alloc((size_t)N_EDGES_*4);
  float* hpre  = (float*)alloc((size_t)N_NODES_*DIN*4);
  float* hgpart= (float*)alloc((size_t)N_GRAPHS*GPARTS*DG*4);
  float* hg    = (float*)alloc((size_t)N_GRAPHS*DG*4);
  float* proj  = (float*)alloc((size_t)N_GRAPHS*G4*4);
  (void)ws_size; (void)in_sizes; (void)n_in; (void)out_size;

  k_count<<<NPART, 256, 0, stream>>>(src, cnt);
  k_pscan<<<1, 1024, 0, stream>>>(cnt);
  k_part<<<NPART, 256, 0, stream>>>(src, dst, cnt, part);
  k_mega<<<N_GRAPHS, 512, 0, stream>>>(x, cnt, part, hpre);
  k_gcn<<<N_GRAPHS*GPARTS, 128, 0, stream>>>(hpre, w_gcn, b_gcn, hgpart);
  k_pool<<<(N_GRAPHS*DG+255)/256, 256, 0, stream>>>(hgpart, hg);
  k_proj<<<N_GRAPHS, 512, 0, stream>>>(hg, w_ih, b_ih, proj);
  k_lstm<<<BWIN, 512, 0, stream>>>(proj, w_hh, b_hh, w_fc, b_fc, out);
}

// Round 4
// 343.494 us; speedup vs baseline: 5.1911x; 1.1596x over previous
//
#include <hip/hip_runtime.h>
#include <hip/hip_bf16.h>

#define N_GRAPHS 200
#define NPG      500
#define N_NODES_ 100000
#define N_EDGES_ 1600000
#define DIN      64
#define DG       128
#define SEQ      20
#define HL       128
#define G4       512
#define BWIN     (N_GRAPHS - SEQ + 1)  // 181
#define NPART    64
#define EPB      (N_EDGES_/NPART)      // 25000
#define NCNT     (N_GRAPHS*NPART)      // 12800
#define GPARTS   8
#define NPPART   63

__device__ __forceinline__ float sigmoidf_(float v){ return 1.0f/(1.0f+expf(-v)); }

// K1: per-(block,graph) edge counts via LDS histogram (no global atomics)
__global__ __launch_bounds__(256) void k_count(const int* __restrict__ src,
                                               int* __restrict__ cnt) {
  __shared__ int bins[N_GRAPHS];
  int b = blockIdx.x, t = threadIdx.x;
  for (int i = t; i < N_GRAPHS; i += 256) bins[i] = 0;
  __syncthreads();
  int e0 = b*EPB;
  for (int i = t; i < EPB; i += 256) atomicAdd(&bins[src[e0+i]/NPG], 1);
  __syncthreads();
  for (int g = t; g < N_GRAPHS; g += 256) cnt[g*NPART + b] = bins[g];
}

// K2: exclusive scan of 12800 counts in one block
__global__ __launch_bounds__(1024) void k_pscan(int* __restrict__ cnt) {
  __shared__ int sA[1024], sB[1024];
  int t = threadIdx.x;
  int base = t*13;
  int loc[13]; int s = 0;
  #pragma unroll
  for (int j = 0; j < 13; ++j) {
    int idx = base + j;
    int v = (idx < NCNT) ? cnt[idx] : 0;
    loc[j] = s; s += v;
  }
  sA[t] = s; __syncthreads();
  int* cur = sA; int* nxt = sB;
  for (int off = 1; off < 1024; off <<= 1) {
    nxt[t] = cur[t] + ((t >= off) ? cur[t-off] : 0);
    __syncthreads();
    int* tmp = cur; cur = nxt; nxt = tmp;
  }
  int excl = cur[t] - s;
  #pragma unroll
  for (int j = 0; j < 13; ++j) {
    int idx = base + j;
    if (idx < NCNT) cnt[idx] = excl + loc[j];
  }
}

// K3: deterministic partition by graph; packed (src_local<<9 | dst_local)
__global__ __launch_bounds__(256) void k_part(const int* __restrict__ src,
                                              const int* __restrict__ dst,
                                              const int* __restrict__ cnt,
                                              int* __restrict__ part) {
  __shared__ int cur[N_GRAPHS];
  int b = blockIdx.x, t = threadIdx.x;
  for (int g = t; g < N_GRAPHS; g += 256) cur[g] = cnt[g*NPART + b];
  __syncthreads();
  int e0 = b*EPB;
  for (int i = t; i < EPB; i += 256) {
    int s = src[e0+i], d = dst[e0+i];
    int g = s / NPG;
    int sl = s - g*NPG, dl = d - g*NPG;
    int pos = atomicAdd(&cur[g], 1);
    part[pos] = (sl << 9) | dl;
  }
}

// K4: per-graph counting sort -> global sorted src list + node metadata
__global__ __launch_bounds__(512) void k_sort(const int* __restrict__ cnt,
    const int* __restrict__ part, unsigned short* __restrict__ sorted_all,
    float* __restrict__ so_all, int* __restrict__ e_end, int* __restrict__ e_deg) {
  __shared__ int indeg[NPG], outdeg[NPG], off[NPG];
  __shared__ int sA[512], sB[512];
  int g = blockIdx.x, t = threadIdx.x;
  int seg0 = cnt[g*NPART];
  int seg1 = (g == N_GRAPHS-1) ? N_EDGES_ : cnt[(g+1)*NPART];
  if (t < NPG) { indeg[t] = 0; outdeg[t] = 0; }
  __syncthreads();
  for (int e = seg0 + t; e < seg1; e += 512) {
    int p = part[e];
    atomicAdd(&indeg[p & 511], 1);
    atomicAdd(&outdeg[p >> 9], 1);
  }
  __syncthreads();
  int v = (t < NPG) ? indeg[t] : 0;
  sA[t] = v; __syncthreads();
  int* cur = sA; int* nxt = sB;
  for (int o = 1; o < 512; o <<= 1) {
    nxt[t] = cur[t] + ((t >= o) ? cur[t-o] : 0);
    __syncthreads();
    int* tmp = cur; cur = nxt; nxt = tmp;
  }
  if (t < NPG) off[t] = cur[t] - v;
  __syncthreads();
  for (int e = seg0 + t; e < seg1; e += 512) {
    int p = part[e];
    int pos = atomicAdd(&off[p & 511], 1);
    sorted_all[seg0 + pos] = (unsigned short)(p >> 9);
  }
  __syncthreads();
  if (t < NPG) {
    so_all[g*NPG + t] = rsqrtf((float)max(outdeg[t], 1));
    e_end[g*NPG + t]  = seg0 + off[t];    // off is now inclusive end
    e_deg[g*NPG + t]  = indeg[t];
  }
}

// K5: aggregation — one wave per node, quarter-wave x 4-unroll per edge
__global__ __launch_bounds__(256) void k_agg(const float* __restrict__ x,
    const float* __restrict__ so_all, const int* __restrict__ e_end,
    const int* __restrict__ e_deg, const unsigned short* __restrict__ sorted_all,
    float* __restrict__ hpre) {
  int t = threadIdx.x;
  int n = (blockIdx.x << 2) + (t >> 6);
  if (n >= N_NODES_) return;
  int lane = t & 63, q = lane >> 4, ql = lane & 15;
  int end = e_end[n], deg = e_deg[n], start = end - deg;
  int g = n / NPG;
  const float4* xg = ((const float4*)x) + (size_t)g*NPG*16;
  const float* sog = so_all + g*NPG;
  float4 acc = make_float4(0.f, 0.f, 0.f, 0.f);
  for (int i = start + (q << 2); i < end; i += 16) {
    int sj[4];
    #pragma unroll
    for (int j = 0; j < 4; ++j) sj[j] = (i + j < end) ? (int)sorted_all[i+j] : -1;
    #pragma unroll
    for (int j = 0; j < 4; ++j) if (sj[j] >= 0) {
      float sc = sog[sj[j]];
      float4 xv = xg[(size_t)sj[j]*16 + ql];
      acc.x += xv.x*sc; acc.y += xv.y*sc; acc.z += xv.z*sc; acc.w += xv.w*sc;
    }
  }
  acc.x += __shfl_xor(acc.x, 16); acc.y += __shfl_xor(acc.y, 16);
  acc.z += __shfl_xor(acc.z, 16); acc.w += __shfl_xor(acc.w, 16);
  acc.x += __shfl_xor(acc.x, 32); acc.y += __shfl_xor(acc.y, 32);
  acc.z += __shfl_xor(acc.z, 32); acc.w += __shfl_xor(acc.w, 32);
  if (q == 0) {
    float sn = rsqrtf((float)max(deg, 1));
    float4 r = make_float4(acc.x*sn, acc.y*sn, acc.z*sn, acc.w*sn);
    ((float4*)hpre)[(size_t)n*16 + ql] = r;
  }
}

// K6: GCN GEMM + ReLU + partial pool. w column in VGPRs.
__global__ __launch_bounds__(128) void k_gcn(const float* __restrict__ hpre,
    const float* __restrict__ w_gcn, const float* __restrict__ b_gcn,
    float* __restrict__ hgpart) {
  int d = threadIdx.x;
  int bb = blockIdx.x;
  int g = bb >> 3, p = bb & 7;
  float wreg[DIN];
  #pragma unroll
  for (int k = 0; k < DIN; ++k) wreg[k] = w_gcn[k*DG + d];
  float bgd = b_gcn[d];
  float psum = 0.0f;
  int n0 = p*NPPART, n1 = min(n0 + NPPART, NPG);
  for (int n = n0; n < n1; ++n) {
    const float4* hp = (const float4*)(hpre + (size_t)(g*NPG + n)*DIN);
    float acc = bgd;
    #pragma unroll
    for (int k4 = 0; k4 < 16; ++k4) {
      float4 h4 = hp[k4];
      acc = fmaf(h4.x, wreg[4*k4+0], acc);
      acc = fmaf(h4.y, wreg[4*k4+1], acc);
      acc = fmaf(h4.z, wreg[4*k4+2], acc);
      acc = fmaf(h4.w, wreg[4*k4+3], acc);
    }
    psum += fmaxf(acc, 0.0f);
  }
  hgpart[(size_t)bb*DG + d] = psum;
}

// K7: combine partials, divide by node count
__global__ void k_pool(const float* __restrict__ hgpart, float* __restrict__ hg) {
  int idx = blockIdx.x*blockDim.x + threadIdx.x;
  if (idx >= N_GRAPHS*DG) return;
  int g = idx >> 7, d = idx & 127;
  float s = 0.0f;
  #pragma unroll
  for (int p = 0; p < GPARTS; ++p) s += hgpart[(size_t)(g*GPARTS+p)*DG + d];
  hg[idx] = s * (1.0f/NPG);
}

// K8: per-graph input projection
__global__ __launch_bounds__(512) void k_proj(const float* __restrict__ hg,
    const float* __restrict__ w_ih, const float* __restrict__ b_ih,
    float* __restrict__ proj) {
  __shared__ __align__(16) float hS[HL];
  int g = blockIdx.x, r = threadIdx.x;
  if (r < HL) hS[r] = hg[g*HL + r];
  __syncthreads();
  const float4* wr = (const float4*)(w_ih + (size_t)r*HL);
  const float4* hv = (const float4*)hS;
  float acc = b_ih[r];
  #pragma unroll
  for (int k4 = 0; k4 < 32; ++k4) {
    float4 w4 = wr[k4]; float4 h4 = hv[k4];
    acc += w4.x*h4.x + w4.y*h4.y + w4.z*h4.z + w4.w*h4.w;
  }
  proj[(size_t)g*G4 + r] = acc;
}

// K9: LSTM, block per window, thread per gate-row, w_hh row in VGPRs
__global__ __launch_bounds__(512) void k_lstm(const float* __restrict__ proj,
    const float* __restrict__ w_hh, const float* __restrict__ b_hh,
    const float* __restrict__ w_fc, const float* __restrict__ b_fc,
    float* __restrict__ out) {
  __shared__ __align__(16) float hS[HL];
  __shared__ float gS[G4];
  int b = blockIdx.x, r = threadIdx.x;
  float wreg[HL];
  const float4* wr = (const float4*)(w_hh + (size_t)r*HL);
  #pragma unroll
  for (int k4 = 0; k4 < 32; ++k4) {
    float4 w4 = wr[k4];
    wreg[k4*4+0]=w4.x; wreg[k4*4+1]=w4.y; wreg[k4*4+2]=w4.z; wreg[k4*4+3]=w4.w;
  }
  float bh = b_hh[r];
  float c = 0.0f;
  if (r < HL) hS[r] = 0.0f;
  __syncthreads();
  for (int l = 0; l < SEQ; ++l) {
    float acc = proj[(size_t)(b+l)*G4 + r] + bh;
    const float4* hv = (const float4*)hS;
    #pragma unroll
    for (int k4 = 0; k4 < 32; ++k4) {
      float4 h4 = hv[k4];
      acc += h4.x*wreg[k4*4] + h4.y*wreg[k4*4+1] + h4.z*wreg[k4*4+2] + h4.w*wreg[k4*4+3];
    }
    gS[r] = acc;
    __syncthreads();
    if (r < HL) {
      float gi = sigmoidf_(gS[r]);
      float gf = sigmoidf_(gS[HL + r]);
      float gg = tanhf(gS[2*HL + r]);
      float go = sigmoidf_(gS[3*HL + r]);
      c = gf*c + gi*gg;
      hS[r] = go * tanhf(c);
    }
    __syncthreads();
  }
  if (r < 64) {
    float s = hS[r]*w_fc[r] + hS[r+64]*w_fc[r+64];
    #pragma unroll
    for (int off = 32; off > 0; off >>= 1) s += __shfl_down(s, off);
    if (r == 0) out[b] = s + b_fc[0];
  }
}

extern "C" void kernel_launch(void* const* d_in, const int* in_sizes, int n_in,
                              void* d_out, int out_size, void* d_ws, size_t ws_size,
                              hipStream_t stream) {
  const float* x     = (const float*)d_in[0];
  const int*   src   = (const int*)d_in[1];
  const int*   dst   = (const int*)d_in[2];
  const float* w_gcn = (const float*)d_in[4];
  const float* b_gcn = (const float*)d_in[5];
  const float* w_ih  = (const float*)d_in[6];
  const float* w_hh  = (const float*)d_in[7];
  const float* b_ih  = (const float*)d_in[8];
  const float* b_hh  = (const float*)d_in[9];
  const float* w_fc  = (const float*)d_in[10];
  const float* b_fc  = (const float*)d_in[11];
  float* out = (float*)d_out;

  char* ws = (char*)d_ws;
  size_t off = 0;
  auto alloc = [&](size_t bytes) -> void* {
    void* p = ws + off; off += (bytes + 255) & ~(size_t)255; return p;
  };
  int* cnt     = (int*)alloc((size_t)NCNT*4);
  int* part    = (int*)alloc((size_t)N_EDGES_*4);
  unsigned short* sorted_all = (unsigned short*)alloc((size_t)N_EDGES_*2);
  float* so_all = (float*)alloc((size_t)N_NODES_*4);
  int* e_end   = (int*)alloc((size_t)N_NODES_*4);
  int* e_deg   = (int*)alloc((size_t)N_NODES_*4);
  float* hpre  = (float*)alloc((size_t)N_NODES_*DIN*4);
  float* hgpart= (float*)alloc((size_t)N_GRAPHS*GPARTS*DG*4);
  float* hg    = (float*)alloc((size_t)N_GRAPHS*DG*4);
  float* proj  = (float*)alloc((size_t)N_GRAPHS*G4*4);
  (void)ws_size; (void)in_sizes; (void)n_in; (void)out_size;

  k_count<<<NPART, 256, 0, stream>>>(src, cnt);
  k_pscan<<<1, 1024, 0, stream>>>(cnt);
  k_part<<<NPART, 256, 0, stream>>>(src, dst, cnt, part);
  k_sort<<<N_GRAPHS, 512, 0, stream>>>(cnt, part, sorted_all, so_all, e_end, e_deg);
  k_agg<<<(N_NODES_+3)/4, 256, 0, stream>>>(x, so_all, e_end, e_deg, sorted_all, hpre);
  k_gcn<<<N_GRAPHS*GPARTS, 128, 0, stream>>>(hpre, w_gcn, b_gcn, hgpart);
  k_pool<<<(N_GRAPHS*DG+255)/256, 256, 0, stream>>>(hgpart, hg);
  k_proj<<<N_GRAPHS, 512, 0, stream>>>(hg, w_ih, b_ih, proj);
  k_lstm<<<BWIN, 512, 0, stream>>>(proj, w_hh, b_hh, w_fc, b_fc, out);
}